// Round 1
// baseline (1173.844 us; speedup 1.0000x reference)
//
#include <hip/hip_runtime.h>

#define HWn 3136
#define W56 56
#define Bn  16
#define CIN0 512
#define WIDc 128
#define OUPc 512

// ---------------- pooled mean over HW: out[bc] = mean(in[bc][:]) ----------------
__global__ __launch_bounds__(256) void pool_mean_kernel(const float* __restrict__ in,
                                                        float* __restrict__ out)
{
    int bc = blockIdx.x;
    const float* p = in + (size_t)bc * HWn;
    float s = 0.f;
    for (int i = threadIdx.x; i < HWn; i += 256) s += p[i];
#pragma unroll
    for (int off = 32; off > 0; off >>= 1) s += __shfl_down(s, off);
    __shared__ float red[4];
    if ((threadIdx.x & 63) == 0) red[threadIdx.x >> 6] = s;
    __syncthreads();
    if (threadIdx.x == 0) out[bc] = (red[0] + red[1] + red[2] + red[3]) / 3136.f;
}

// ---------------- channel mask: mask[b][o] = (pooled[b]·W[o] + bias[o] > 0) ----------------
__global__ void chan_mask_kernel(const float* __restrict__ pooled, const float* __restrict__ Wm,
                                 const float* __restrict__ bias, float* __restrict__ mask,
                                 int Cin, int Cout)
{
    int b = blockIdx.x, o = threadIdx.x;
    if (o >= Cout) return;
    const float* pr = pooled + (size_t)b * Cin;
    const float* wr = Wm + (size_t)o * Cin;
    float s = bias[o];
    for (int c = 0; c < Cin; ++c) s = fmaf(pr[c], wr[c], s);
    mask[b * Cout + o] = (s > 0.f) ? 1.f : 0.f;
}

// ---------------- spatial mask: smask[b][p] = (sum_c x[b][c][p]*smw[c] + smb > 0) ----------------
__global__ __launch_bounds__(256) void spatial_mask_kernel(const float* __restrict__ x,
        const float* __restrict__ smw, const float* __restrict__ smb, float* __restrict__ smask)
{
    __shared__ float ws[512];
    int b = blockIdx.x;
    for (int i = threadIdx.x; i < 512; i += 256) ws[i] = smw[i];
    __syncthreads();
    int p = blockIdx.y * 256 + threadIdx.x;
    if (p >= HWn) return;
    const float* xp = x + (size_t)b * CIN0 * HWn + p;
    float s = smb[0];
#pragma unroll 8
    for (int c = 0; c < CIN0; ++c) s = fmaf(xp[(size_t)c * HWn], ws[c], s);
    smask[b * HWn + p] = (s > 0.f) ? 1.f : 0.f;
}

// ---------------- 3x3 max dilation of spatial mask ----------------
__global__ __launch_bounds__(256) void dilate_kernel(const float* __restrict__ sm, float* __restrict__ sd)
{
    int b = blockIdx.x;
    int p = blockIdx.y * 256 + threadIdx.x;
    if (p >= HWn) return;
    int py = p / W56, px = p % W56;
    float m = 0.f;
    for (int dy = -1; dy <= 1; ++dy) {
        int sy = py + dy; if (sy < 0 || sy >= W56) continue;
        for (int dx = -1; dx <= 1; ++dx) {
            int sx = px + dx; if (sx < 0 || sx >= W56) continue;
            m = fmaxf(m, sm[b * HWn + sy * W56 + sx]);
        }
    }
    sd[b * HWn + p] = m;
}

// ---------------- transpose w2 (o,c,tap) -> (tap,c,o) ----------------
__global__ __launch_bounds__(256) void transpose_w2_kernel(const float* __restrict__ w2,
                                                           float* __restrict__ w2t)
{
    int e = blockIdx.x * 256 + threadIdx.x;     // < 9*128*128
    if (e >= 9 * 128 * 128) return;
    int o = e & 127;
    int c = (e >> 7) & 127;
    int tap = e >> 14;
    w2t[e] = w2[((size_t)o * 128 + c) * 9 + tap];
}

// ---------------- tiled 1x1 conv (GEMM): out = act(W@in + b) * cmask * pmask ----------------
template<int CIN, int COUT, bool RELU>
__global__ __launch_bounds__(256) void conv1x1_kernel(
    const float* __restrict__ in,    // [B][CIN][HW]
    const float* __restrict__ Wg,    // [COUT][CIN]
    const float* __restrict__ bias,  // [COUT]
    const float* __restrict__ cmask, // [B][COUT]
    const float* __restrict__ pmask, // [B][HW]
    float* __restrict__ out)         // [B][COUT][HW]
{
    __shared__ float wT[32][68];     // [k][o], padded (stride 272B, 16B-aligned)
    __shared__ float xs[32][128];    // [k][p]
    const int b  = blockIdx.z;
    const int o0 = blockIdx.y * 64;
    const int p0 = blockIdx.x * 128;
    const int tid = threadIdx.x;
    const int to = tid >> 5;         // 0..7
    const int tp = tid & 31;         // 0..31
    const int ob = to * 8;
    const int pb = tp * 4;

    float acc[8][4];
#pragma unroll
    for (int i = 0; i < 8; ++i)
#pragma unroll
        for (int j = 0; j < 4; ++j) acc[i][j] = 0.f;

    const float* inB = in + (size_t)b * CIN * HWn;

    for (int kc = 0; kc < CIN; kc += 32) {
        __syncthreads();
#pragma unroll
        for (int i = 0; i < 8; ++i) {          // 64x32 W tile
            int e = tid + i * 256;
            int o = e >> 5, k = e & 31;
            wT[k][o] = Wg[(size_t)(o0 + o) * CIN + kc + k];
        }
#pragma unroll
        for (int i = 0; i < 16; ++i) {         // 32x128 X tile
            int e = tid + i * 256;
            int k = e >> 7, p = e & 127;
            int gp = p0 + p; if (gp >= HWn) gp = HWn - 1;
            xs[k][p] = inB[(size_t)(kc + k) * HWn + gp];
        }
        __syncthreads();
#pragma unroll
        for (int k = 0; k < 32; ++k) {
            float4 w0 = *(const float4*)&wT[k][ob];
            float4 w1v = *(const float4*)&wT[k][ob + 4];
            float4 xv = *(const float4*)&xs[k][pb];
            float wr[8] = {w0.x, w0.y, w0.z, w0.w, w1v.x, w1v.y, w1v.z, w1v.w};
            float xr[4] = {xv.x, xv.y, xv.z, xv.w};
#pragma unroll
            for (int i = 0; i < 8; ++i)
#pragma unroll
                for (int j = 0; j < 4; ++j)
                    acc[i][j] = fmaf(wr[i], xr[j], acc[i][j]);
        }
    }

    if (p0 + pb < HWn) {
        float4 pmv = *(const float4*)&pmask[(size_t)b * HWn + p0 + pb];
#pragma unroll
        for (int i = 0; i < 8; ++i) {
            int o = o0 + ob + i;
            float cm = cmask[b * COUT + o];
            float bs = bias[o];
            float4 v;
            v.x = acc[i][0] + bs; v.y = acc[i][1] + bs;
            v.z = acc[i][2] + bs; v.w = acc[i][3] + bs;
            if (RELU) {
                v.x = fmaxf(v.x, 0.f); v.y = fmaxf(v.y, 0.f);
                v.z = fmaxf(v.z, 0.f); v.w = fmaxf(v.w, 0.f);
            }
            v.x = v.x * cm * pmv.x; v.y = v.y * cm * pmv.y;
            v.z = v.z * cm * pmv.z; v.w = v.w * cm * pmv.w;
            *(float4*)&out[((size_t)b * COUT + o) * HWn + p0 + pb] = v;
        }
    }
}

// ---------------- tiled 3x3 conv (9 shifted GEMMs): h2 = relu(conv3x3(h1)+b)*cmask*pmask ----------------
__global__ __launch_bounds__(256) void conv3x3_kernel(
    const float* __restrict__ in,    // [B][128][HW]
    const float* __restrict__ Wt,    // [9][128][128]  (tap, c, o)
    const float* __restrict__ bias,  // [128]
    const float* __restrict__ cmask, // [B][128]
    const float* __restrict__ pmask, // [B][HW]
    float* __restrict__ out)         // [B][128][HW]
{
    __shared__ float wT[32][68];
    __shared__ float xs[32][128];
    const int b  = blockIdx.z;
    const int o0 = blockIdx.y * 64;
    const int p0 = blockIdx.x * 128;
    const int tid = threadIdx.x;
    const int to = tid >> 5;
    const int tp = tid & 31;
    const int ob = to * 8;
    const int pb = tp * 4;

    float acc[8][4];
#pragma unroll
    for (int i = 0; i < 8; ++i)
#pragma unroll
        for (int j = 0; j < 4; ++j) acc[i][j] = 0.f;

    const float* inB = in + (size_t)b * WIDc * HWn;

    for (int tap = 0; tap < 9; ++tap) {
        int dy = tap / 3 - 1, dx = tap % 3 - 1;
        for (int kc = 0; kc < WIDc; kc += 32) {
            __syncthreads();
#pragma unroll
            for (int i = 0; i < 8; ++i) {      // W tile: Wt[tap][kc+k][o0+o]
                int e = tid + i * 256;
                int o = e & 63, k = e >> 6;
                wT[k][o] = Wt[((size_t)tap * 128 + kc + k) * 128 + o0 + o];
            }
#pragma unroll
            for (int i = 0; i < 16; ++i) {     // shifted X tile
                int e = tid + i * 256;
                int k = e >> 7, pp = e & 127;
                int q = p0 + pp;
                float v = 0.f;
                if (q < HWn) {
                    int py = q / W56, px = q % W56;
                    int sy = py + dy, sx = px + dx;
                    if (sy >= 0 && sy < W56 && sx >= 0 && sx < W56)
                        v = inB[(size_t)(kc + k) * HWn + sy * W56 + sx];
                }
                xs[k][pp] = v;
            }
            __syncthreads();
#pragma unroll
            for (int k = 0; k < 32; ++k) {
                float4 w0 = *(const float4*)&wT[k][ob];
                float4 w1v = *(const float4*)&wT[k][ob + 4];
                float4 xv = *(const float4*)&xs[k][pb];
                float wr[8] = {w0.x, w0.y, w0.z, w0.w, w1v.x, w1v.y, w1v.z, w1v.w};
                float xr[4] = {xv.x, xv.y, xv.z, xv.w};
#pragma unroll
                for (int i = 0; i < 8; ++i)
#pragma unroll
                    for (int j = 0; j < 4; ++j)
                        acc[i][j] = fmaf(wr[i], xr[j], acc[i][j]);
            }
        }
    }

    if (p0 + pb < HWn) {
        float4 pmv = *(const float4*)&pmask[(size_t)b * HWn + p0 + pb];
#pragma unroll
        for (int i = 0; i < 8; ++i) {
            int o = o0 + ob + i;
            float cm = cmask[b * WIDc + o];
            float bs = bias[o];
            float4 v;
            v.x = fmaxf(acc[i][0] + bs, 0.f); v.y = fmaxf(acc[i][1] + bs, 0.f);
            v.z = fmaxf(acc[i][2] + bs, 0.f); v.w = fmaxf(acc[i][3] + bs, 0.f);
            v.x = v.x * cm * pmv.x; v.y = v.y * cm * pmv.y;
            v.z = v.z * cm * pmv.z; v.w = v.w * cm * pmv.w;
            *(float4*)&out[((size_t)b * WIDc + o) * HWn + p0 + pb] = v;
        }
    }
}

// ---------------- per-(b,c) row means and column means of h3 ----------------
__global__ __launch_bounds__(128) void rowcol_mean_kernel(const float* __restrict__ h3,
        float* __restrict__ xh, float* __restrict__ xw)
{
    __shared__ float t[HWn];
    int bc = blockIdx.x;
    const float* p = h3 + (size_t)bc * HWn;
    for (int i = threadIdx.x; i < HWn; i += 128) t[i] = p[i];
    __syncthreads();
    int tid = threadIdx.x;
    if (tid < 56) {
        float s = 0.f;
#pragma unroll
        for (int i = 0; i < 56; ++i) s += t[tid * 56 + i];
        xh[(size_t)bc * 56 + tid] = s / 56.f;
    } else if (tid >= 64 && tid < 120) {
        int c = tid - 64;
        float s = 0.f;
#pragma unroll
        for (int i = 0; i < 56; ++i) s += t[i * 56 + c];
        xw[(size_t)bc * 56 + c] = s / 56.f;
    }
}

// ---------------- squeeze conv + hswish: y[b][m][t], t in [0,112) ----------------
__global__ __launch_bounds__(256) void ca_y_kernel(const float* __restrict__ xh,
        const float* __restrict__ xw, const float* __restrict__ w1c,
        const float* __restrict__ b1c, float* __restrict__ y)
{
    int b = blockIdx.x;
    int t = blockIdx.y;   // 0..111
    __shared__ float src[512];
    __shared__ float part[16][17];
    for (int c = threadIdx.x; c < 512; c += 256)
        src[c] = (t < 56) ? xh[((size_t)b * 512 + c) * 56 + t]
                          : xw[((size_t)b * 512 + c) * 56 + (t - 56)];
    __syncthreads();
    int m  = threadIdx.x & 15;
    int cp = threadIdx.x >> 4;   // 0..15
    float s = 0.f;
#pragma unroll 8
    for (int i = 0; i < 32; ++i) {
        int c = cp * 32 + i;
        s = fmaf(w1c[(size_t)m * 512 + c], src[c], s);
    }
    part[m][cp] = s;
    __syncthreads();
    if (threadIdx.x < 16) {
        float v = b1c[threadIdx.x];
#pragma unroll
        for (int i = 0; i < 16; ++i) v += part[threadIdx.x][i];
        float r6 = fminf(fmaxf(v + 3.f, 0.f), 6.f);
        y[((size_t)b * 16 + threadIdx.x) * 112 + t] = v * r6 / 6.f;
    }
}

// ---------------- excite convs + sigmoid: ah[b][o][r], aw[b][o][col] ----------------
__global__ __launch_bounds__(512) void ca_a_kernel(const float* __restrict__ y,
        const float* __restrict__ wh, const float* __restrict__ bh,
        const float* __restrict__ wwp, const float* __restrict__ bw,
        float* __restrict__ ah, float* __restrict__ aw)
{
    int r = blockIdx.x;       // 0..55
    int side = blockIdx.y;    // 0: h, 1: w
    int b = blockIdx.z;
    int o = threadIdx.x;      // 0..511
    __shared__ float ys[16];
    if (threadIdx.x < 16)
        ys[threadIdx.x] = y[((size_t)b * 16 + threadIdx.x) * 112 + side * 56 + r];
    __syncthreads();
    const float* wmat = side ? wwp : wh;
    float s = (side ? bw : bh)[o];
#pragma unroll
    for (int m = 0; m < 16; ++m) s = fmaf(wmat[o * 16 + m], ys[m], s);
    float sig = 1.f / (1.f + expf(-s));
    (side ? aw : ah)[((size_t)b * 512 + o) * 56 + r] = sig;
}

// ---------------- final: out = relu(h3*ah*aw + x), in-place on d_out ----------------
__global__ __launch_bounds__(256) void finalize_kernel(const float* __restrict__ x,
        const float* __restrict__ ah, const float* __restrict__ aw, float* __restrict__ out)
{
    int e = blockIdx.x * 256 + threadIdx.x;    // quad index, total 16*512*784
    int pq = e % 784;
    int bc = e / 784;
    int p = pq * 4;
    int py = p / 56, px = p % 56;
    float4 h = *((const float4*)out + e);
    float4 xv = *((const float4*)x + e);
    float a_h = ah[(size_t)bc * 56 + py];
    float4 a_w = *(const float4*)&aw[(size_t)bc * 56 + px];
    float4 v;
    v.x = fmaxf(h.x * a_h * a_w.x + xv.x, 0.f);
    v.y = fmaxf(h.y * a_h * a_w.y + xv.y, 0.f);
    v.z = fmaxf(h.z * a_h * a_w.z + xv.z, 0.f);
    v.w = fmaxf(h.w * a_h * a_w.w + xv.w, 0.f);
    *((float4*)out + e) = v;
}

extern "C" void kernel_launch(void* const* d_in, const int* in_sizes, int n_in,
                              void* d_out, int out_size, void* d_ws, size_t ws_size,
                              hipStream_t stream)
{
    (void)in_sizes; (void)n_in; (void)out_size; (void)ws_size;
    const float* x     = (const float*)d_in[0];
    const float* sm_w  = (const float*)d_in[1];
    const float* sm_b  = (const float*)d_in[2];
    const float* cm1_w = (const float*)d_in[3];
    const float* cm1_b = (const float*)d_in[4];
    const float* cm2_w = (const float*)d_in[5];
    const float* cm2_b = (const float*)d_in[6];
    const float* cm3_w = (const float*)d_in[7];
    const float* cm3_b = (const float*)d_in[8];
    const float* w1    = (const float*)d_in[9];
    const float* b1    = (const float*)d_in[10];
    const float* w2    = (const float*)d_in[11];
    const float* b2    = (const float*)d_in[12];
    const float* w3    = (const float*)d_in[13];
    const float* b3    = (const float*)d_in[14];
    const float* ca_w1 = (const float*)d_in[15];
    const float* ca_b1 = (const float*)d_in[16];
    const float* ca_wh = (const float*)d_in[17];
    const float* ca_bh = (const float*)d_in[18];
    const float* ca_ww = (const float*)d_in[19];
    const float* ca_bw = (const float*)d_in[20];
    float* out = (float*)d_out;

    float* ws = (float*)d_ws;
    float* pooled_x  = ws;                       // 8192
    float* cm1m      = pooled_x + 8192;          // 2048
    float* smask     = cm1m + 2048;              // 50176
    float* sdil      = smask + 50176;            // 50176
    float* h1        = sdil + 50176;             // 6422528
    float* pooled_h1 = h1 + 6422528;             // 2048
    float* cm2m      = pooled_h1 + 2048;         // 2048
    float* h2        = cm2m + 2048;              // 6422528
    float* pooled_h2 = h2 + 6422528;             // 2048
    float* cm3m      = pooled_h2 + 2048;         // 8192
    float* w2t       = cm3m + 8192;              // 147456
    float* xh        = w2t + 147456;             // 458752
    float* xwm       = xh + 458752;              // 458752
    float* yb        = xwm + 458752;             // 28672
    float* ah        = yb + 28672;               // 458752
    float* aw        = ah + 458752;              // 458752

    pool_mean_kernel<<<Bn * CIN0, 256, 0, stream>>>(x, pooled_x);
    chan_mask_kernel<<<Bn, 128, 0, stream>>>(pooled_x, cm1_w, cm1_b, cm1m, 512, 128);
    spatial_mask_kernel<<<dim3(Bn, 13), 256, 0, stream>>>(x, sm_w, sm_b, smask);
    dilate_kernel<<<dim3(Bn, 13), 256, 0, stream>>>(smask, sdil);
    transpose_w2_kernel<<<576, 256, 0, stream>>>(w2, w2t);

    conv1x1_kernel<512, 128, true><<<dim3(25, 2, Bn), 256, 0, stream>>>(
        x, w1, b1, cm1m, sdil, h1);

    pool_mean_kernel<<<Bn * 128, 256, 0, stream>>>(h1, pooled_h1);
    chan_mask_kernel<<<Bn, 128, 0, stream>>>(pooled_h1, cm2_w, cm2_b, cm2m, 128, 128);

    conv3x3_kernel<<<dim3(25, 2, Bn), 256, 0, stream>>>(h1, w2t, b2, cm2m, smask, h2);

    pool_mean_kernel<<<Bn * 128, 256, 0, stream>>>(h2, pooled_h2);
    chan_mask_kernel<<<Bn, 512, 0, stream>>>(pooled_h2, cm3_w, cm3_b, cm3m, 128, 512);

    conv1x1_kernel<128, 512, false><<<dim3(25, 8, Bn), 256, 0, stream>>>(
        h2, w3, b3, cm3m, smask, out);

    rowcol_mean_kernel<<<Bn * OUPc, 128, 0, stream>>>(out, xh, xwm);
    ca_y_kernel<<<dim3(Bn, 112), 256, 0, stream>>>(xh, xwm, ca_w1, ca_b1, yb);
    ca_a_kernel<<<dim3(W56, 2, Bn), 512, 0, stream>>>(yb, ca_wh, ca_bh, ca_ww, ca_bw, ah, aw);
    finalize_kernel<<<25088, 256, 0, stream>>>(x, ah, aw, out);
}

// Round 2
// 663.471 us; speedup vs baseline: 1.7692x; 1.7692x over previous
//
#include <hip/hip_runtime.h>

#define HWn 3136
#define W56 56
#define Bn  16
#define CIN0 512

typedef unsigned short ushortT;
typedef __attribute__((ext_vector_type(8))) short bf16x8;
typedef __attribute__((ext_vector_type(4))) float f32x4;

__device__ inline ushortT bf_hi(float v) {
    unsigned u = __float_as_uint(v);
    unsigned r = u + 0x7FFFu + ((u >> 16) & 1u);
    return (ushortT)(r >> 16);
}
__device__ inline float bf_f(ushortT h) { return __uint_as_float(((unsigned)h) << 16); }

// ---------------- pooled mean over HW (NCHW input): out[bc] = mean ----------------
__global__ __launch_bounds__(256) void pool_mean_kernel(const float* __restrict__ in,
                                                        float* __restrict__ out)
{
    int bc = blockIdx.x;
    const float* p = in + (size_t)bc * HWn;
    float s = 0.f;
    for (int i = threadIdx.x; i < HWn; i += 256) s += p[i];
#pragma unroll
    for (int off = 32; off > 0; off >>= 1) s += __shfl_down(s, off);
    __shared__ float red[4];
    if ((threadIdx.x & 63) == 0) red[threadIdx.x >> 6] = s;
    __syncthreads();
    if (threadIdx.x == 0) out[bc] = (red[0] + red[1] + red[2] + red[3]) / 3136.f;
}

// ---------------- zero small f32 buffer ----------------
__global__ void zero_kernel(float* __restrict__ p, int n)
{
    int i = blockIdx.x * 256 + threadIdx.x;
    if (i < n) p[i] = 0.f;
}

// ---------------- pooled mean over P of transposed split-bf16 [B][P][128] ----------------
__global__ __launch_bounds__(256) void pool_meanT_kernel(const ushortT* __restrict__ hi,
        const ushortT* __restrict__ lo, float* __restrict__ pooled)
{
    int b = blockIdx.x, slice = blockIdx.y;
    int t = threadIdx.x;
    int c4 = (t & 31) * 4, rg = t >> 5;
    float a0 = 0.f, a1 = 0.f, a2 = 0.f, a3 = 0.f;
    for (int it = 0; it < 49; ++it) {
        int p = slice * 392 + rg + it * 8;
        size_t base = ((size_t)b * HWn + p) * 128 + c4;
        ushort4 h4 = *(const ushort4*)&hi[base];
        ushort4 l4 = *(const ushort4*)&lo[base];
        a0 += bf_f(h4.x) + bf_f(l4.x);
        a1 += bf_f(h4.y) + bf_f(l4.y);
        a2 += bf_f(h4.z) + bf_f(l4.z);
        a3 += bf_f(h4.w) + bf_f(l4.w);
    }
    __shared__ float red[8][128];
    red[rg][c4] = a0; red[rg][c4 + 1] = a1; red[rg][c4 + 2] = a2; red[rg][c4 + 3] = a3;
    __syncthreads();
    if (t < 128) {
        float s = 0.f;
#pragma unroll
        for (int g = 0; g < 8; ++g) s += red[g][t];
        atomicAdd(&pooled[b * 128 + t], s * (1.f / 3136.f));
    }
}

// ---------------- channel mask ----------------
__global__ void chan_mask_kernel(const float* __restrict__ pooled, const float* __restrict__ Wm,
                                 const float* __restrict__ bias, float* __restrict__ mask,
                                 int Cin, int Cout)
{
    int b = blockIdx.x, o = threadIdx.x;
    if (o >= Cout) return;
    const float* pr = pooled + (size_t)b * Cin;
    const float* wr = Wm + (size_t)o * Cin;
    float s = bias[o];
    for (int c = 0; c < Cin; ++c) s = fmaf(pr[c], wr[c], s);
    mask[b * Cout + o] = (s > 0.f) ? 1.f : 0.f;
}

// ---------------- spatial mask ----------------
__global__ __launch_bounds__(256) void spatial_mask_kernel(const float* __restrict__ x,
        const float* __restrict__ smw, const float* __restrict__ smb, float* __restrict__ smask)
{
    __shared__ float ws[512];
    int b = blockIdx.x;
    for (int i = threadIdx.x; i < 512; i += 256) ws[i] = smw[i];
    __syncthreads();
    int p = blockIdx.y * 256 + threadIdx.x;
    if (p >= HWn) return;
    const float* xp = x + (size_t)b * CIN0 * HWn + p;
    float s = smb[0];
#pragma unroll 8
    for (int c = 0; c < CIN0; ++c) s = fmaf(xp[(size_t)c * HWn], ws[c], s);
    smask[b * HWn + p] = (s > 0.f) ? 1.f : 0.f;
}

// ---------------- 3x3 max dilation ----------------
__global__ __launch_bounds__(256) void dilate_kernel(const float* __restrict__ sm, float* __restrict__ sd)
{
    int b = blockIdx.x;
    int p = blockIdx.y * 256 + threadIdx.x;
    if (p >= HWn) return;
    int py = p / W56, px = p % W56;
    float m = 0.f;
    for (int dy = -1; dy <= 1; ++dy) {
        int sy = py + dy; if (sy < 0 || sy >= W56) continue;
        for (int dx = -1; dx <= 1; ++dx) {
            int sx = px + dx; if (sx < 0 || sx >= W56) continue;
            m = fmaxf(m, sm[b * HWn + sy * W56 + sx]);
        }
    }
    sd[b * HWn + p] = m;
}

// ---------------- weight split kernels ----------------
__global__ void split_w_kernel(const float* __restrict__ w, ushortT* __restrict__ hi,
                               ushortT* __restrict__ lo, int n)
{
    int i = blockIdx.x * 256 + threadIdx.x;
    if (i >= n) return;
    float v = w[i];
    ushortT h = bf_hi(v);
    hi[i] = h;
    lo[i] = bf_hi(v - bf_f(h));
}

__global__ void split_w2_kernel(const float* __restrict__ w2, ushortT* __restrict__ hi,
                                ushortT* __restrict__ lo)
{
    int e = blockIdx.x * 256 + threadIdx.x;   // [tap][o][c]
    if (e >= 9 * 128 * 128) return;
    int c = e & 127, o = (e >> 7) & 127, tap = e >> 14;
    float v = w2[((size_t)o * 128 + c) * 9 + tap];
    ushortT h = bf_hi(v);
    hi[e] = h;
    lo[e] = bf_hi(v - bf_f(h));
}

// ---------------- MFMA split-bf16 conv (1x1 or 3x3-as-9-taps) ----------------
// Block: 128 O x 128 P, K-step 32, 4 waves of 64x64 (4x4 fragments of 16x16x32).
template<int KC, int TAPS, bool RELU, bool IN_F32, bool OUT_F32>
__global__ __launch_bounds__(256) void mfma_conv_kernel(
    const float* __restrict__ in_f32,
    const ushortT* __restrict__ in_hi, const ushortT* __restrict__ in_lo,
    const ushortT* __restrict__ wh, const ushortT* __restrict__ wl,
    const float* __restrict__ bias, const float* __restrict__ cmask,
    const float* __restrict__ pmask,
    float* __restrict__ out_f32, ushortT* __restrict__ out_hi, ushortT* __restrict__ out_lo,
    int Cout)
{
    __shared__ __align__(16) ushortT As_hi[128 * 40], As_lo[128 * 40];
    __shared__ __align__(16) ushortT Bs_hi[128 * 40], Bs_lo[128 * 40];
    __shared__ float s_bias[128], s_cm[128];

    const int b  = blockIdx.z;
    const int o0 = blockIdx.y * 128;
    const int p0 = blockIdx.x * 128;
    const int tid = threadIdx.x;
    const int lane = tid & 63;
    const int g  = lane >> 4;
    const int lc = lane & 15;
    const int wid = tid >> 6;
    const int wm = wid >> 1, wn = wid & 1;

    if (tid < 128) {
        s_bias[tid] = bias[o0 + tid];
        s_cm[tid]   = cmask[b * Cout + o0 + tid];
    }

    // fragment LDS element offsets
    int aoff[4], boff[4];
#pragma unroll
    for (int m = 0; m < 4; ++m) aoff[m] = (wm * 64 + m * 16 + lc) * 40 + g * 8;
#pragma unroll
    for (int n = 0; n < 4; ++n) {
        int pl = wn * 64 + n * 16 + lc;
        boff[n] = pl * 40 + ((g ^ (pl & 3)) * 8);
    }

    f32x4 acc[4][4];
#pragma unroll
    for (int m = 0; m < 4; ++m)
#pragma unroll
        for (int n = 0; n < 4; ++n) acc[m][n] = (f32x4){0.f, 0.f, 0.f, 0.f};

    for (int tap = 0; tap < TAPS; ++tap) {
        const int dy = (TAPS == 9) ? (tap / 3 - 1) : 0;
        const int dx = (TAPS == 9) ? (tap % 3 - 1) : 0;
        for (int kc = 0; kc < KC; kc += 32) {
            __syncthreads();
            // ---- stage A (weights) : 128 rows x 32 k, hi+lo ----
#pragma unroll
            for (int i = 0; i < 2; ++i) {
                int unit = tid + i * 256;          // 0..511
                int row = unit >> 2, ch = unit & 3;
                size_t srow = (TAPS == 9) ? ((size_t)tap * 128 + row) * 128
                                          : (size_t)(o0 + row) * KC;
                uint4 vh = *(const uint4*)(wh + srow + kc + ch * 8);
                uint4 vl = *(const uint4*)(wl + srow + kc + ch * 8);
                *(uint4*)&As_hi[row * 40 + ch * 8] = vh;
                *(uint4*)&As_lo[row * 40 + ch * 8] = vl;
            }
            // ---- stage B (activations) ----
            if (IN_F32) {
                const float* inB = in_f32 + (size_t)b * KC * HWn;
#pragma unroll
                for (int j = 0; j < 4; ++j) {
                    int cr = (tid >> 5) + j * 8;       // 0..31
                    int p4 = (tid & 31) * 4;
                    float4 xv = make_float4(0.f, 0.f, 0.f, 0.f);
                    if (p0 + p4 < HWn)
                        xv = *(const float4*)&inB[(size_t)(kc + cr) * HWn + p0 + p4];
                    float vv[4] = {xv.x, xv.y, xv.z, xv.w};
#pragma unroll
                    for (int e = 0; e < 4; ++e) {
                        int prow = p4 + e;
                        ushortT h = bf_hi(vv[e]);
                        ushortT l = bf_hi(vv[e] - bf_f(h));
                        int kk = ((cr >> 3) ^ (prow & 3)) * 8 + (cr & 7);
                        Bs_hi[prow * 40 + kk] = h;
                        Bs_lo[prow * 40 + kk] = l;
                    }
                }
            } else {
#pragma unroll
                for (int i = 0; i < 2; ++i) {
                    int unit = tid + i * 256;
                    int row = unit >> 2, ch = unit & 3;
                    int pg = p0 + row;
                    int q = pg, valid;
                    if (TAPS == 9) {
                        int py = pg / 56, px = pg % 56;
                        int sy = py + dy, sx = px + dx;
                        valid = (pg < HWn) && (sy >= 0) && (sy < 56) && (sx >= 0) && (sx < 56);
                        q = sy * 56 + sx;
                    } else {
                        valid = (pg < HWn);
                    }
                    uint4 vh = make_uint4(0u, 0u, 0u, 0u), vl = vh;
                    if (valid) {
                        size_t sbase = ((size_t)b * HWn + q) * 128 + kc + ch * 8;
                        vh = *(const uint4*)(in_hi + sbase);
                        vl = *(const uint4*)(in_lo + sbase);
                    }
                    int chs = ch ^ (row & 3);
                    *(uint4*)&Bs_hi[row * 40 + chs * 8] = vh;
                    *(uint4*)&Bs_lo[row * 40 + chs * 8] = vl;
                }
            }
            __syncthreads();
            // ---- compute: 16 frags x 3 MFMA ----
            bf16x8 a_h[4], a_l[4];
#pragma unroll
            for (int m = 0; m < 4; ++m) {
                a_h[m] = *(const bf16x8*)&As_hi[aoff[m]];
                a_l[m] = *(const bf16x8*)&As_lo[aoff[m]];
            }
#pragma unroll
            for (int n = 0; n < 4; ++n) {
                bf16x8 b_h = *(const bf16x8*)&Bs_hi[boff[n]];
                bf16x8 b_l = *(const bf16x8*)&Bs_lo[boff[n]];
#pragma unroll
                for (int m = 0; m < 4; ++m) {
                    acc[m][n] = __builtin_amdgcn_mfma_f32_16x16x32_bf16(a_h[m], b_h, acc[m][n], 0, 0, 0);
                    acc[m][n] = __builtin_amdgcn_mfma_f32_16x16x32_bf16(a_h[m], b_l, acc[m][n], 0, 0, 0);
                    acc[m][n] = __builtin_amdgcn_mfma_f32_16x16x32_bf16(a_l[m], b_h, acc[m][n], 0, 0, 0);
                }
            }
        }
    }

    // ---- epilogue ----
#pragma unroll
    for (int m = 0; m < 4; ++m) {
        int ob = wm * 64 + m * 16 + g * 4;         // local o base (4 consecutive via r)
        f32x4 b4 = *(const f32x4*)&s_bias[ob];
        f32x4 c4 = *(const f32x4*)&s_cm[ob];
#pragma unroll
        for (int n = 0; n < 4; ++n) {
            int p = p0 + wn * 64 + n * 16 + lc;
            if (p >= HWn) continue;
            float pm = pmask[b * HWn + p];
            float v[4];
#pragma unroll
            for (int r = 0; r < 4; ++r) {
                float t = acc[m][n][r] + b4[r];
                if (RELU) t = fmaxf(t, 0.f);
                v[r] = t * c4[r] * pm;
            }
            if (OUT_F32) {
#pragma unroll
                for (int r = 0; r < 4; ++r)
                    out_f32[((size_t)b * Cout + o0 + ob + r) * HWn + p] = v[r];
            } else {
                ushort4 H, L;
                H.x = bf_hi(v[0]); L.x = bf_hi(v[0] - bf_f(H.x));
                H.y = bf_hi(v[1]); L.y = bf_hi(v[1] - bf_f(H.y));
                H.z = bf_hi(v[2]); L.z = bf_hi(v[2] - bf_f(H.z));
                H.w = bf_hi(v[3]); L.w = bf_hi(v[3] - bf_f(H.w));
                size_t base = ((size_t)b * HWn + p) * 128 + ob;
                *(ushort4*)&out_hi[base] = H;
                *(ushort4*)&out_lo[base] = L;
            }
        }
    }
}

// ---------------- coord-att: row/col means of h3 (NCHW f32) ----------------
__global__ __launch_bounds__(128) void rowcol_mean_kernel(const float* __restrict__ h3,
        float* __restrict__ xh, float* __restrict__ xw)
{
    __shared__ float t[HWn];
    int bc = blockIdx.x;
    const float* p = h3 + (size_t)bc * HWn;
    for (int i = threadIdx.x; i < HWn; i += 128) t[i] = p[i];
    __syncthreads();
    int tid = threadIdx.x;
    if (tid < 56) {
        float s = 0.f;
#pragma unroll
        for (int i = 0; i < 56; ++i) s += t[tid * 56 + i];
        xh[(size_t)bc * 56 + tid] = s / 56.f;
    } else if (tid >= 64 && tid < 120) {
        int c = tid - 64;
        float s = 0.f;
#pragma unroll
        for (int i = 0; i < 56; ++i) s += t[i * 56 + c];
        xw[(size_t)bc * 56 + c] = s / 56.f;
    }
}

__global__ __launch_bounds__(256) void ca_y_kernel(const float* __restrict__ xh,
        const float* __restrict__ xw, const float* __restrict__ w1c,
        const float* __restrict__ b1c, float* __restrict__ y)
{
    int b = blockIdx.x;
    int t = blockIdx.y;
    __shared__ float src[512];
    __shared__ float part[16][17];
    for (int c = threadIdx.x; c < 512; c += 256)
        src[c] = (t < 56) ? xh[((size_t)b * 512 + c) * 56 + t]
                          : xw[((size_t)b * 512 + c) * 56 + (t - 56)];
    __syncthreads();
    int m  = threadIdx.x & 15;
    int cp = threadIdx.x >> 4;
    float s = 0.f;
#pragma unroll 8
    for (int i = 0; i < 32; ++i) {
        int c = cp * 32 + i;
        s = fmaf(w1c[(size_t)m * 512 + c], src[c], s);
    }
    part[m][cp] = s;
    __syncthreads();
    if (threadIdx.x < 16) {
        float v = b1c[threadIdx.x];
#pragma unroll
        for (int i = 0; i < 16; ++i) v += part[threadIdx.x][i];
        float r6 = fminf(fmaxf(v + 3.f, 0.f), 6.f);
        y[((size_t)b * 16 + threadIdx.x) * 112 + t] = v * r6 / 6.f;
    }
}

__global__ __launch_bounds__(512) void ca_a_kernel(const float* __restrict__ y,
        const float* __restrict__ wh, const float* __restrict__ bh,
        const float* __restrict__ wwp, const float* __restrict__ bw,
        float* __restrict__ ah, float* __restrict__ aw)
{
    int r = blockIdx.x;
    int side = blockIdx.y;
    int b = blockIdx.z;
    int o = threadIdx.x;
    __shared__ float ys[16];
    if (threadIdx.x < 16)
        ys[threadIdx.x] = y[((size_t)b * 16 + threadIdx.x) * 112 + side * 56 + r];
    __syncthreads();
    const float* wmat = side ? wwp : wh;
    float s = (side ? bw : bh)[o];
#pragma unroll
    for (int m = 0; m < 16; ++m) s = fmaf(wmat[o * 16 + m], ys[m], s);
    float sig = 1.f / (1.f + expf(-s));
    (side ? aw : ah)[((size_t)b * 512 + o) * 56 + r] = sig;
}

__global__ __launch_bounds__(256) void finalize_kernel(const float* __restrict__ x,
        const float* __restrict__ ah, const float* __restrict__ aw, float* __restrict__ out)
{
    int e = blockIdx.x * 256 + threadIdx.x;
    int pq = e % 784;
    int bc = e / 784;
    int p = pq * 4;
    int py = p / 56, px = p % 56;
    float4 h = *((const float4*)out + e);
    float4 xv = *((const float4*)x + e);
    float a_h = ah[(size_t)bc * 56 + py];
    float4 a_w = *(const float4*)&aw[(size_t)bc * 56 + px];
    float4 v;
    v.x = fmaxf(h.x * a_h * a_w.x + xv.x, 0.f);
    v.y = fmaxf(h.y * a_h * a_w.y + xv.y, 0.f);
    v.z = fmaxf(h.z * a_h * a_w.z + xv.z, 0.f);
    v.w = fmaxf(h.w * a_h * a_w.w + xv.w, 0.f);
    *((float4*)out + e) = v;
}

extern "C" void kernel_launch(void* const* d_in, const int* in_sizes, int n_in,
                              void* d_out, int out_size, void* d_ws, size_t ws_size,
                              hipStream_t stream)
{
    (void)in_sizes; (void)n_in; (void)out_size; (void)ws_size;
    const float* x     = (const float*)d_in[0];
    const float* sm_w  = (const float*)d_in[1];
    const float* sm_b  = (const float*)d_in[2];
    const float* cm1_w = (const float*)d_in[3];
    const float* cm1_b = (const float*)d_in[4];
    const float* cm2_w = (const float*)d_in[5];
    const float* cm2_b = (const float*)d_in[6];
    const float* cm3_w = (const float*)d_in[7];
    const float* cm3_b = (const float*)d_in[8];
    const float* w1    = (const float*)d_in[9];
    const float* b1    = (const float*)d_in[10];
    const float* w2    = (const float*)d_in[11];
    const float* b2    = (const float*)d_in[12];
    const float* w3    = (const float*)d_in[13];
    const float* b3    = (const float*)d_in[14];
    const float* ca_w1 = (const float*)d_in[15];
    const float* ca_b1 = (const float*)d_in[16];
    const float* ca_wh = (const float*)d_in[17];
    const float* ca_bh = (const float*)d_in[18];
    const float* ca_ww = (const float*)d_in[19];
    const float* ca_bw = (const float*)d_in[20];
    float* out = (float*)d_out;

    // ---- workspace layout ----
    float* fp = (float*)d_ws;
    float* pooled_x  = fp;              fp += 8192;
    float* cm1m      = fp;              fp += 2048;
    float* smask     = fp;              fp += 50176;
    float* sdil      = fp;              fp += 50176;
    float* pooled_h1 = fp;              fp += 2048;
    float* cm2m      = fp;              fp += 2048;
    float* pooled_h2 = fp;              fp += 2048;
    float* cm3m      = fp;              fp += 8192;
    ushortT* up = (ushortT*)fp;
    ushortT* w1h = up;                  up += 65536;
    ushortT* w1l = up;                  up += 65536;
    ushortT* w2h = up;                  up += 147456;
    ushortT* w2l = up;                  up += 147456;
    ushortT* w3h = up;                  up += 65536;
    ushortT* w3l = up;                  up += 65536;
    ushortT* h1h = up;                  up += 6422528;
    ushortT* h1l = up;                  up += 6422528;
    ushortT* h2h = up;                  up += 6422528;
    ushortT* h2l = up;                  up += 6422528;
    // coord-att scratch aliases h1 (dead after conv2)
    float* xh  = (float*)h1h;
    float* xwm = xh + 458752;
    float* yb  = xwm + 458752;
    float* ah  = yb + 28672;
    float* aw  = ah + 458752;

    zero_kernel<<<8, 256, 0, stream>>>(pooled_h1, 2048);
    zero_kernel<<<8, 256, 0, stream>>>(pooled_h2, 2048);
    pool_mean_kernel<<<Bn * CIN0, 256, 0, stream>>>(x, pooled_x);
    chan_mask_kernel<<<Bn, 128, 0, stream>>>(pooled_x, cm1_w, cm1_b, cm1m, 512, 128);
    spatial_mask_kernel<<<dim3(Bn, 13), 256, 0, stream>>>(x, sm_w, sm_b, smask);
    dilate_kernel<<<dim3(Bn, 13), 256, 0, stream>>>(smask, sdil);
    split_w_kernel<<<256, 256, 0, stream>>>(w1, w1h, w1l, 65536);
    split_w2_kernel<<<576, 256, 0, stream>>>(w2, w2h, w2l);
    split_w_kernel<<<256, 256, 0, stream>>>(w3, w3h, w3l, 65536);

    // conv1: 1x1, K=512, relu, masks cm1*sdil -> h1 (transposed split bf16)
    mfma_conv_kernel<512, 1, true, true, false><<<dim3(25, 1, Bn), 256, 0, stream>>>(
        x, nullptr, nullptr, w1h, w1l, b1, cm1m, sdil, nullptr, h1h, h1l, 128);

    pool_meanT_kernel<<<dim3(Bn, 8), 256, 0, stream>>>(h1h, h1l, pooled_h1);
    chan_mask_kernel<<<Bn, 128, 0, stream>>>(pooled_h1, cm2_w, cm2_b, cm2m, 128, 128);

    // conv2: 3x3 as 9 taps, K=128, relu, masks cm2*smask -> h2
    mfma_conv_kernel<128, 9, true, false, false><<<dim3(25, 1, Bn), 256, 0, stream>>>(
        nullptr, h1h, h1l, w2h, w2l, b2, cm2m, smask, nullptr, h2h, h2l, 128);

    pool_meanT_kernel<<<dim3(Bn, 8), 256, 0, stream>>>(h2h, h2l, pooled_h2);
    chan_mask_kernel<<<Bn, 512, 0, stream>>>(pooled_h2, cm3_w, cm3_b, cm3m, 128, 512);

    // conv3: 1x1, K=128, no relu, masks cm3*smask -> out (NCHW f32)
    mfma_conv_kernel<128, 1, false, false, true><<<dim3(25, 4, Bn), 256, 0, stream>>>(
        nullptr, h2h, h2l, w3h, w3l, b3, cm3m, smask, out, nullptr, nullptr, 512);

    rowcol_mean_kernel<<<Bn * 512, 128, 0, stream>>>(out, xh, xwm);
    ca_y_kernel<<<dim3(Bn, 112), 256, 0, stream>>>(xh, xwm, ca_w1, ca_b1, yb);
    ca_a_kernel<<<dim3(W56, 2, Bn), 512, 0, stream>>>(yb, ca_wh, ca_bh, ca_ww, ca_bw, ah, aw);
    finalize_kernel<<<25088, 256, 0, stream>>>(x, ah, aw, out);
}